// Round 10
// baseline (264.555 us; speedup 1.0000x reference)
//
#include <hip/hip_runtime.h>
#include <hip/hip_bf16.h>

// Problem constants (B=8, C=512, H=W=64, HEADS=8, HEAD_DIM=64)
#define BATCH 8
#define CDIM 512
#define NPIX 4096            // 64*64
#define NHEAD 8
#define HDIM 64
#define ATT_SCALE 0.125f     // HEAD_DIM^-0.5
#define L2EPS 1e-12f
#define STRIP 8              // y-rows per dwconv block

typedef __attribute__((ext_vector_type(8))) short short8;   // 8 bf16 (4 VGPRs)
typedef __attribute__((ext_vector_type(4))) short bf16x4;   // 4 bf16 (8B)
typedef __attribute__((ext_vector_type(4))) float f32x4;    // MFMA C/D

typedef const __attribute__((address_space(1))) void* gas_ptr;
typedef __attribute__((address_space(3))) void* las_ptr;

__device__ __forceinline__ void ld_lds16(const void* g, void* l) {
    // async global->LDS, 16B/lane. LDS dest = wave-uniform base + lane*16.
    __builtin_amdgcn_global_load_lds((gas_ptr)g, (las_ptr)l, 16, 0, 0);
}

__device__ __forceinline__ short f2bs(float f) {
    __hip_bfloat16 h = __float2bfloat16(f);
    return *reinterpret_cast<short*>(&h);
}

__device__ __forceinline__ float bs2f(short s) {
    unsigned u = ((unsigned)(unsigned short)s) << 16;
    return __builtin_bit_cast(float, u);
}

// ---------------------------------------------------------------------------
// shared 128x128-tile 2-phase GEMM core (round-1/2 verified): dbuf LDS,
// prefetch-issued-first, involution bank swizzle (slot ^= (row>>1)&3).
// ---------------------------------------------------------------------------
template <int KLEN, int ASTR, int BSTR>
__device__ __forceinline__ void gemm128_core(const short* __restrict__ Ag,
                                             const short* __restrict__ Bg,
                                             short* lds,   // [2][8192] shorts
                                             f32x4 acc[4][4], int tid) {
    const int wave = tid >> 6, lane = tid & 63;
    const int am = (wave >> 1) * 64, bn = (wave & 1) * 64;
    const int lrow = lane & 15;
    const int kslot = ((lane >> 4) ^ ((lrow >> 1) & 3)) * 8;
    const int sslot = ((lane & 3) ^ ((lane >> 3) & 3)) * 8;
    const int srow = wave * 16 + (lane >> 2);

    {
        short* As = lds;
        short* Bs = lds + 4096;
#pragma unroll
        for (int i = 0; i < 2; ++i) {
            const int r = srow + i * 64;
            const int off = (i * 256 + wave * 64) * 8;
            ld_lds16(Ag + (size_t)r * ASTR + sslot, As + off);
            ld_lds16(Bg + (size_t)r * BSTR + sslot, Bs + off);
        }
    }
    __syncthreads();

    int cur = 0;
    for (int k0 = 0; k0 < KLEN; k0 += 32) {
        if (k0 + 32 < KLEN) {
            short* As = lds + (cur ^ 1) * 8192;
            short* Bs = lds + (cur ^ 1) * 8192 + 4096;
#pragma unroll
            for (int i = 0; i < 2; ++i) {
                const int r = srow + i * 64;
                const int off = (i * 256 + wave * 64) * 8;
                ld_lds16(Ag + (size_t)r * ASTR + (k0 + 32) + sslot, As + off);
                ld_lds16(Bg + (size_t)r * BSTR + (k0 + 32) + sslot, Bs + off);
            }
        }
        const short* As = lds + cur * 8192;
        const short* Bs = lds + cur * 8192 + 4096;
        short8 afrag[4], bfrag[4];
#pragma unroll
        for (int i = 0; i < 4; ++i)
            afrag[i] = *(const short8*)&As[(am + i * 16 + lrow) * 32 + kslot];
#pragma unroll
        for (int j = 0; j < 4; ++j)
            bfrag[j] = *(const short8*)&Bs[(bn + j * 16 + lrow) * 32 + kslot];
#pragma unroll
        for (int i = 0; i < 4; ++i)
#pragma unroll
            for (int j = 0; j < 4; ++j)
                acc[i][j] = __builtin_amdgcn_mfma_f32_16x16x32_bf16(afrag[i], bfrag[j],
                                                                   acc[i][j], 0, 0, 0);
        __syncthreads();
        cur ^= 1;
    }
}

// ---------------------------------------------------------------------------
// 1) fused depthwise 3x3 (pad 1) + bf16 cast. 512 threads = 8 waves x 4 ch
//    -> block c-span 32: xdT transpose stores are 64B-contiguous per pixel.
//    Writes xd [b][c][n] and xdT [b][n][c].
// ---------------------------------------------------------------------------
__global__ __launch_bounds__(512) void dwconv_t(const float* __restrict__ x,
                                                const float* __restrict__ w,
                                                short* __restrict__ xd,
                                                short* __restrict__ xdT) {
    __shared__ float tile[2][32][65];
    const int t = threadIdx.x;
    const int lane = t & 63;          // x coordinate
    const int wv = t >> 6;            // 0..7
    const int y0 = blockIdx.x * STRIP;
    const int c0 = blockIdx.y * 32;
    const int b  = blockIdx.z;

    float wgt[4][9];
    float r0[4], r1[4], r2[4];
    const float* xb[4];
#pragma unroll
    for (int i = 0; i < 4; ++i) {
        const int c = c0 + wv * 4 + i;
        const float* wp = w + c * 9;
#pragma unroll
        for (int j = 0; j < 9; ++j) wgt[i][j] = wp[j];
        xb[i] = x + ((size_t)(b * CDIM + c)) * NPIX + lane;
        r0[i] = (y0 > 0) ? xb[i][(y0 - 1) * 64] : 0.f;
        r1[i] = xb[i][y0 * 64];
        r2[i] = xb[i][(y0 + 1) * 64];
    }

    for (int yy = 0; yy < STRIP; yy += 2) {
        const int y = y0 + yy;
        const bool l2 = (y + 2 < 64);
        const bool l3 = (yy < STRIP - 2) && (y + 3 < 64);
        float nA[4], nB[4];
#pragma unroll
        for (int i = 0; i < 4; ++i) {
            nA[i] = l2 ? xb[i][(y + 2) * 64] : 0.f;
            nB[i] = l3 ? xb[i][(y + 3) * 64] : 0.f;
        }

#pragma unroll
        for (int i = 0; i < 4; ++i) {
            // row y: window (r0, r1, r2)
            {
                float cl = wgt[i][0] * r0[i] + wgt[i][3] * r1[i] + wgt[i][6] * r2[i];
                float cm = wgt[i][1] * r0[i] + wgt[i][4] * r1[i] + wgt[i][7] * r2[i];
                float cr = wgt[i][2] * r0[i] + wgt[i][5] * r1[i] + wgt[i][8] * r2[i];
                float lft = __shfl_up(cl, 1);
                if (lane == 0) lft = 0.f;
                float rgt = __shfl_down(cr, 1);
                if (lane == 63) rgt = 0.f;
                const float val = lft + cm + rgt;
                tile[0][wv * 4 + i][lane] = val;
                xd[((size_t)(b * CDIM + c0 + wv * 4 + i)) * NPIX + y * 64 + lane]
                    = f2bs(val);
            }
            // row y+1: window (r1, r2, nA)
            {
                float cl = wgt[i][0] * r1[i] + wgt[i][3] * r2[i] + wgt[i][6] * nA[i];
                float cm = wgt[i][1] * r1[i] + wgt[i][4] * r2[i] + wgt[i][7] * nA[i];
                float cr = wgt[i][2] * r1[i] + wgt[i][5] * r2[i] + wgt[i][8] * nA[i];
                float lft = __shfl_up(cl, 1);
                if (lane == 0) lft = 0.f;
                float rgt = __shfl_down(cr, 1);
                if (lane == 63) rgt = 0.f;
                const float val = lft + cm + rgt;
                tile[1][wv * 4 + i][lane] = val;
                xd[((size_t)(b * CDIM + c0 + wv * 4 + i)) * NPIX + (y + 1) * 64 + lane]
                    = f2bs(val);
            }
        }
        __syncthreads();
        {
            // 512 threads: 64 pixels x 8 channel-quads; per pixel 8 threads
            // x 8B = 64B contiguous (full cacheline, 16B-aligned stores).
            const int n_l = t >> 3;
            const int cq = (t & 7) * 4;
#pragma unroll
            for (int s = 0; s < 2; ++s) {
                bf16x4 pk;
#pragma unroll
                for (int j = 0; j < 4; ++j) pk[j] = f2bs(tile[s][cq + j][n_l]);
                short* dst = xdT + ((size_t)b * NPIX + (y + s) * 64 + n_l) * CDIM + c0 + cq;
                *(bf16x4*)dst = pk;
            }
        }
        __syncthreads();
#pragma unroll
        for (int i = 0; i < 4; ++i) { r0[i] = r2[i]; r1[i] = nA[i]; r2[i] = nB[i]; }
    }
}

// ---------------------------------------------------------------------------
// 2) weight casts: q,k,v,proj natural bf16 + Wv TRANSPOSED bf16 (for M-assembly)
// ---------------------------------------------------------------------------
__global__ __launch_bounds__(256) void cast_weights(const float* __restrict__ s0,
                                                    const float* __restrict__ s1,
                                                    const float* __restrict__ s2,
                                                    const float* __restrict__ s3,
                                                    short* __restrict__ d0,
                                                    short* __restrict__ d1,
                                                    short* __restrict__ d2,
                                                    short* __restrict__ d3,
                                                    short* __restrict__ d4) {
    const int i = blockIdx.x * 256 + threadIdx.x;
    const int m = blockIdx.y;
    if (m < 4) {
        const float* s = (m == 0) ? s0 : (m == 1) ? s1 : (m == 2) ? s2 : s3;
        short* d = (m == 0) ? d0 : (m == 1) ? d1 : (m == 2) ? d2 : d3;
        d[i] = f2bs(s[i]);
    } else {
        // d4[c*512 + e] = bf16(v_w[e*512 + c])
        d4[i] = f2bs(s2[(size_t)(i & 511) * 512 + (i >> 9)]);
    }
}

// ---------------------------------------------------------------------------
// 3) Gram partials, K split 8-WAYS: Gp[z][m][n'] = sum_{n in K-eighth}
//    xd[m,n]*xd[n',n], z = b*8 + kh. 1024 blocks = 4/CU (TLP hides the
//    2-phase barrier drain; m97 mechanism).
// ---------------------------------------------------------------------------
__global__ __launch_bounds__(256) void gram_part(const short* __restrict__ xd,
                                                 float* __restrict__ Gp) {
    __shared__ __align__(16) short lds[2 * 8192];
    const int tid = threadIdx.x;
    const int n0 = blockIdx.x * 128;
    const int m0 = blockIdx.y * 128;
    const int z  = blockIdx.z;
    const int b = z >> 3, kh = z & 7;
    const short* Ag = xd + ((size_t)(b * CDIM + m0)) * NPIX + kh * 512;
    const short* Bg = xd + ((size_t)(b * CDIM + n0)) * NPIX + kh * 512;
    f32x4 acc[4][4] = {};
    gemm128_core<512, NPIX, NPIX>(Ag, Bg, lds, acc, tid);

    const int wave = tid >> 6, lane = tid & 63;
    const int am = (wave >> 1) * 64, bn = (wave & 1) * 64;
    const int crow = (lane >> 4) * 4, ccol = lane & 15;
    float* outp = Gp + (size_t)z * 262144;
#pragma unroll
    for (int i = 0; i < 4; ++i)
#pragma unroll
        for (int j = 0; j < 4; ++j)
#pragma unroll
            for (int r = 0; r < 4; ++r)
                outp[(size_t)(m0 + am + i * 16 + crow + r) * 512 + n0 + bn + j * 16 + ccol]
                    = acc[i][j][r];
}

// ---------------------------------------------------------------------------
// 4) reduce 8 Gram partials + cast to bf16 (straight vectorized streams)
// ---------------------------------------------------------------------------
__global__ __launch_bounds__(256) void gram_cast(const float* __restrict__ Gp,
                                                 short* __restrict__ G16) {
    const int i4 = blockIdx.x * 256 + threadIdx.x;   // 524288 threads
    const int b = i4 >> 16;
    const int r4 = (i4 & 65535) * 4;
    const float* base = Gp + (size_t)(8 * b) * 262144 + r4;
    float s0 = 0.f, s1 = 0.f, s2 = 0.f, s3 = 0.f;
#pragma unroll
    for (int kh = 0; kh < 8; ++kh) {
        f32x4 v = *(const f32x4*)&base[(size_t)kh * 262144];
        s0 += v[0]; s1 += v[1]; s2 += v[2]; s3 += v[3];
    }
    bf16x4 o;
    o[0] = f2bs(s0); o[1] = f2bs(s1); o[2] = f2bs(s2); o[3] = f2bs(s3);
    *(bf16x4*)&G16[(size_t)b * 262144 + r4] = o;
}

// ---------------------------------------------------------------------------
// 5) [Wq;Wk;Wv] x G  -> QKVG[b][1536][512] bf16 (G symmetric: rows as B-op)
// ---------------------------------------------------------------------------
__global__ __launch_bounds__(256) void gemm_qkvG(const short* __restrict__ Wq,
                                                 const short* __restrict__ Wk,
                                                 const short* __restrict__ Wv,
                                                 const short* __restrict__ G16,
                                                 short* __restrict__ QKVG) {
    __shared__ __align__(16) short lds[2 * 8192];
    const int tid = threadIdx.x;
    const int n0 = blockIdx.x * 128;
    const int ot = blockIdx.y;                 // 0..11
    const int g = ot >> 2, o0 = (ot & 3) * 128;
    const int b = blockIdx.z;
    const short* W = (g == 0) ? Wq : (g == 1) ? Wk : Wv;
    const short* Ag = W + (size_t)o0 * CDIM;
    const short* Bg = G16 + (size_t)b * 262144 + (size_t)n0 * 512;
    f32x4 acc[4][4] = {};
    gemm128_core<512, 512, 512>(Ag, Bg, lds, acc, tid);

    const int wave = tid >> 6, lane = tid & 63;
    const int am = (wave >> 1) * 64, bn = (wave & 1) * 64;
    const int crow = (lane >> 4) * 4, ccol = lane & 15;
    short* Yg = QKVG + ((size_t)b * 1536 + g * 512 + o0) * 512;
#pragma unroll
    for (int i = 0; i < 4; ++i)
#pragma unroll
        for (int j = 0; j < 4; ++j)
#pragma unroll
            for (int r = 0; r < 4; ++r)
                Yg[(size_t)(am + i * 16 + crow + r) * 512 + n0 + bn + j * 16 + ccol]
                    = f2bs(acc[i][j][r]);
}

// ---------------------------------------------------------------------------
// 6) norms: rnorm[m][b][row] = 1/max(sqrt(QKVG[b][m,row,:] . W_m[row,:]), eps)
// ---------------------------------------------------------------------------
__global__ __launch_bounds__(256) void norms_dot(const short* __restrict__ QKVG,
                                                 const short* __restrict__ Wq,
                                                 const short* __restrict__ Wk,
                                                 const short* __restrict__ Wv,
                                                 float* __restrict__ rnorm) {
    const int tid = threadIdx.x, w = tid >> 6, lane = tid & 63;
#pragma unroll
    for (int it = 0; it < 4; ++it) {
        const int R = blockIdx.x * 16 + w * 4 + it;      // 0..12287
        const int b = R / 1536;
        const int mr = R - b * 1536;
        const int m = mr >> 9, row = mr & 511;
        const short* qr = QKVG + (size_t)R * 512 + lane * 8;
        const short* wr = ((m == 0) ? Wq : (m == 1) ? Wk : Wv) + (size_t)row * 512 + lane * 8;
        short8 a = *(const short8*)qr;
        short8 ww = *(const short8*)wr;
        float s = 0.f;
#pragma unroll
        for (int t = 0; t < 8; ++t) s += bs2f(a[t]) * bs2f(ww[t]);
        s += __shfl_xor(s, 1);  s += __shfl_xor(s, 2);
        s += __shfl_xor(s, 4);  s += __shfl_xor(s, 8);
        s += __shfl_xor(s, 16); s += __shfl_xor(s, 32);
        if (lane == 0)
            rnorm[m * 4096 + b * 512 + row] = 1.f / fmaxf(sqrtf(fmaxf(s, 0.f)), L2EPS);
    }
}

// ---------------------------------------------------------------------------
// 7) per-(b,h): A1 = QG_h * Wk_h^T (64x64, K=512) -> softmax (+norm scales,
//    rv folded) -> MT[b][c][h*64+d] = sum_e WvT[c][h*64+e] * P'[d][e].
//    blockIdx.y in [0,4): each block assembles 128 of the 512 c-rows.
// ---------------------------------------------------------------------------
__global__ __launch_bounds__(256) void attn_small(const short* __restrict__ QKVG,
                                                  const short* __restrict__ Wk,
                                                  const short* __restrict__ WvT,
                                                  const float* __restrict__ rnorm,
                                                  short* __restrict__ MT) {
    __shared__ __align__(16) short Qs[64 * 32];
    __shared__ __align__(16) short Ks[64 * 32];
    __shared__ __align__(16) short Pl[64 * 72];
    const int tid = threadIdx.x, wave = tid >> 6, lane = tid & 63;
    const int bh = blockIdx.x, b = bh >> 3, h = bh & 7;
    const int cq = blockIdx.y;                 // c-quarter for MT assembly
    const int lrow = lane & 15;
    const int kslot = ((lane >> 4) ^ ((lrow >> 1) & 3)) * 8;
    const int sslot = ((lane & 3) ^ ((lane >> 3) & 3)) * 8;
    const int srow = tid >> 2;
    const short* qg = QKVG + ((size_t)b * 1536 + h * 64) * 512;   // QG rows d
    const short* kg = Wk + (size_t)(h * 64) * 512;                // Wk_h rows e
    f32x4 acc[4] = {};
    for (int k0 = 0; k0 < 512; k0 += 32) {
        ld_lds16(qg + (size_t)srow * 512 + k0 + sslot, Qs + wave * 512);
        ld_lds16(kg + (size_t)srow * 512 + k0 + sslot, Ks + wave * 512);
        __syncthreads();
        short8 af = *(const short8*)&Qs[(wave * 16 + lrow) * 32 + kslot];
#pragma unroll
        for (int j = 0; j < 4; ++j) {
            short8 bf = *(const short8*)&Ks[(j * 16 + lrow) * 32 + kslot];
            acc[j] = __builtin_amdgcn_mfma_f32_16x16x32_bf16(af, bf, acc[j], 0, 0, 0);
        }
        __syncthreads();
    }
    const int crow = (lane >> 4) * 4, ccol = lane & 15;
    const float* rq = rnorm + bh * 64;
    const float* rk = rnorm + 4096 + bh * 64;
    const float* rv = rnorm + 8192 + bh * 64;
    float rkv[4], rvv[4];
#pragma unroll
    for (int j = 0; j < 4; ++j) { rkv[j] = rk[j * 16 + ccol]; rvv[j] = rv[j * 16 + ccol]; }
#pragma unroll
    for (int r = 0; r < 4; ++r) {
        const int row = wave * 16 + crow + r;                    // d
        const float rqs = ATT_SCALE * rq[row];
        float L[4];
#pragma unroll
        for (int j = 0; j < 4; ++j) L[j] = acc[j][r] * rqs * rkv[j];
        float m = fmaxf(fmaxf(L[0], L[1]), fmaxf(L[2], L[3]));
        m = fmaxf(m, __shfl_xor(m, 1)); m = fmaxf(m, __shfl_xor(m, 2));
        m = fmaxf(m, __shfl_xor(m, 4)); m = fmaxf(m, __shfl_xor(m, 8));
        float p[4], s = 0.f;
#pragma unroll
        for (int j = 0; j < 4; ++j) { p[j] = expf(L[j] - m); s += p[j]; }
        s += __shfl_xor(s, 1); s += __shfl_xor(s, 2);
        s += __shfl_xor(s, 4); s += __shfl_xor(s, 8);
        const float inv = 1.f / s;
#pragma unroll
        for (int j = 0; j < 4; ++j)
            Pl[row * 72 + j * 16 + ccol] = f2bs(p[j] * inv * rvv[j]);
    }
    __syncthreads();
    // MT assembly (this block's 128 c-rows): C[c][d] = sum_e WvT[c][he] P'[d][e]
    const int lk2 = (lane >> 4) * 8;
    const short* wvt = WvT + h * 64;
    const int am2 = cq * 128 + wave * 32;
    f32x4 acc2[2][4] = {};
#pragma unroll
    for (int ks = 0; ks < 2; ++ks) {
        short8 bfr[4];
#pragma unroll
        for (int j2 = 0; j2 < 4; ++j2)
            bfr[j2] = *(const short8*)&Pl[(j2 * 16 + lrow) * 72 + ks * 32 + lk2];
#pragma unroll
        for (int i2 = 0; i2 < 2; ++i2) {
            short8 afr = *(const short8*)&wvt[(size_t)(am2 + i2 * 16 + lrow) * 512 + ks * 32 + lk2];
#pragma unroll
            for (int j2 = 0; j2 < 4; ++j2)
                acc2[i2][j2] = __builtin_amdgcn_mfma_f32_16x16x32_bf16(afr, bfr[j2],
                                                                      acc2[i2][j2], 0, 0, 0);
        }
    }
#pragma unroll
    for (int i2 = 0; i2 < 2; ++i2)
#pragma unroll
        for (int j2 = 0; j2 < 4; ++j2)
#pragma unroll
            for (int r = 0; r < 4; ++r)
                MT[((size_t)b * 512 + am2 + i2 * 16 + crow + r) * 512 + h * 64 + j2 * 16 + ccol]
                    = f2bs(acc2[i2][j2][r]);
}

// ---------------------------------------------------------------------------
// 8) F = Wp * M, SPLIT-K=2 (256 blocks = 1/CU):
//    fp32 partials Fp[kh][b][o][c]; f_cast reduces + casts to bf16.
// ---------------------------------------------------------------------------
__global__ __launch_bounds__(256) void gemm_projF(const short* __restrict__ Wp,
                                                  const short* __restrict__ MT,
                                                  float* __restrict__ Fp) {
    __shared__ __align__(16) short lds[2 * 8192];
    const int tid = threadIdx.x;
    const int n0 = blockIdx.x * 128;      // c
    const int o0 = blockIdx.y * 128;      // o
    const int z  = blockIdx.z;            // b*2 + kh
    const int b = z >> 1, kh = z & 1;
    const short* Ag = Wp + (size_t)o0 * CDIM + kh * 256;
    const short* Bg = MT + (size_t)b * 262144 + (size_t)n0 * 512 + kh * 256;
    f32x4 acc[4][4] = {};
    gemm128_core<256, 512, 512>(Ag, Bg, lds, acc, tid);

    const int wave = tid >> 6, lane = tid & 63;
    const int am = (wave >> 1) * 64, bn = (wave & 1) * 64;
    const int crow = (lane >> 4) * 4, ccol = lane & 15;
    float* Fg = Fp + (size_t)kh * 8 * 262144 + (size_t)b * 262144;
#pragma unroll
    for (int i = 0; i < 4; ++i)
#pragma unroll
        for (int j = 0; j < 4; ++j)
#pragma unroll
            for (int r = 0; r < 4; ++r)
                Fg[(size_t)(o0 + am + i * 16 + crow + r) * 512 + n0 + bn + j * 16 + ccol]
                    = acc[i][j][r];
}

// 8b) reduce 2 proj partials + cast to bf16
__global__ __launch_bounds__(256) void f_cast(const float* __restrict__ Fp,
                                              short* __restrict__ F) {
    const int i4 = blockIdx.x * 256 + threadIdx.x;   // 524288 threads
    const size_t off = (size_t)i4 * 4;
    f32x4 a = *(const f32x4*)&Fp[off];
    f32x4 c = *(const f32x4*)&Fp[(size_t)8 * 262144 + off];
    bf16x4 o;
#pragma unroll
    for (int t = 0; t < 4; ++t) o[t] = f2bs(a[t] + c[t]);
    *(bf16x4*)&F[off] = o;
}

// ---------------------------------------------------------------------------
// 9) out = F * xd  (B-operand = xdT rows, K=c) -> fp32 out[b][o][n]
// ---------------------------------------------------------------------------
__global__ __launch_bounds__(256) void gemm_final(const short* __restrict__ F,
                                                  const short* __restrict__ XT,
                                                  float* __restrict__ Y) {
    __shared__ __align__(16) short lds[2 * 8192];
    const int tid = threadIdx.x;
    const int n0 = blockIdx.x * 128;
    const int o0 = blockIdx.y * 128;
    const int b  = blockIdx.z;
    const short* Ag = F + (size_t)b * 262144 + (size_t)o0 * 512;
    const short* Bg = XT + ((size_t)b * NPIX + n0) * CDIM;
    f32x4 acc[4][4] = {};
    gemm128_core<512, 512, 512>(Ag, Bg, lds, acc, tid);

    const int wave = tid >> 6, lane = tid & 63;
    const int am = (wave >> 1) * 64, bn = (wave & 1) * 64;
    const int crow = (lane >> 4) * 4, ccol = lane & 15;
#pragma unroll
    for (int i = 0; i < 4; ++i)
#pragma unroll
        for (int j = 0; j < 4; ++j)
#pragma unroll
            for (int r = 0; r < 4; ++r) {
                const int om = o0 + am + i * 16 + crow + r;
                const int on = n0 + bn + j * 16 + ccol;
                Y[((size_t)(b * CDIM + om)) * NPIX + on] = acc[i][j][r];
            }
}

// ---------------------------------------------------------------------------
extern "C" void kernel_launch(void* const* d_in, const int* in_sizes, int n_in,
                              void* d_out, int out_size, void* d_ws, size_t ws_size,
                              hipStream_t stream) {
    (void)in_sizes; (void)n_in; (void)out_size; (void)ws_size;
    const float* x      = (const float*)d_in[0];
    const float* dw_w   = (const float*)d_in[1];
    const float* q_w    = (const float*)d_in[2];
    const float* k_w    = (const float*)d_in[3];
    const float* v_w    = (const float*)d_in[4];
    const float* proj_w = (const float*)d_in[5];
    float* out = (float*)d_out;

    const size_t SZ = (size_t)BATCH * CDIM * NPIX;    // 16,777,216 elements
    short* xd   = (short*)d_ws;                        // SZ shorts (32 MB)
    short* xdT  = xd + SZ;                             // SZ shorts (32 MB)
    float* Gp   = (float*)(xdT + SZ);                  // 64 * 262144 fp32 (67 MB)
    short* G16  = (short*)(Gp + (size_t)64 * 262144);  // 8 * 262144 bf16 (4 MB)
    short* QKVG = G16 + (size_t)8 * 262144;            // 8*1536*512 bf16 (12 MB)
    float* rnorm= (float*)(QKVG + (size_t)8 * 1536 * 512);  // 3*8*512 fp32
    short* MTb  = (short*)(rnorm + 12288);             // 8*512*512 bf16 (4 MB)
    short* Fb   = MTb + (size_t)8 * 262144;            // 8*512*512 bf16 (4 MB)
    short* wqb  = Fb + (size_t)8 * 262144;             // 5 x 262144 bf16
    short* wkb  = wqb + 262144;
    short* wvb  = wkb + 262144;
    short* wpb  = wvb + 262144;
    short* wvtb = wpb + 262144;
    float* Fp   = (float*)(wvtb + 262144);             // 2*8*262144 fp32 (16 MB)

    // 1) fused dwconv3x3 + bf16 cast -> xd [b][c][n] and xdT [b][n][c]
    dwconv_t<<<dim3(64 / STRIP, CDIM / 32, BATCH), 512, 0, stream>>>(x, dw_w, xd, xdT);

    // 2) weights -> bf16 (+ transposed Wv)
    cast_weights<<<dim3(1024, 5), 256, 0, stream>>>(q_w, k_w, v_w, proj_w,
                                                    wqb, wkb, wvb, wpb, wvtb);

    // 3) Gram partials (K split 8-ways: 1024 blocks = 4/CU) + 4) reduce/cast
    gram_part<<<dim3(4, 4, 64), 256, 0, stream>>>(xd, Gp);
    gram_cast<<<dim3(2048), 256, 0, stream>>>(Gp, G16);

    // 5) [Wq;Wk;Wv] x G
    gemm_qkvG<<<dim3(4, 12, 8), 256, 0, stream>>>(wqb, wkb, wvb, G16, QKVG);

    // 6) L2-norm reciprocals (quadratic-form diagonals)
    norms_dot<<<dim3(768), 256, 0, stream>>>(QKVG, wqb, wkb, wvb, rnorm);

    // 7) per-head 64x64 attention + split M^T assembly (256 blocks)
    attn_small<<<dim3(64, 4), 256, 0, stream>>>(QKVG, wkb, wvtb, rnorm, MTb);

    // 8) F = Wp * M (split-K=2: 256 blocks) + reduce/cast
    gemm_projF<<<dim3(4, 4, 16), 256, 0, stream>>>(wpb, MTb, Fp);
    f_cast<<<dim3(2048), 256, 0, stream>>>(Fp, Fb);

    // 9) out = F * xd
    gemm_final<<<dim3(32, 4, 8), 256, 0, stream>>>(Fb, xdT, out);
}

// Round 11
// 242.775 us; speedup vs baseline: 1.0897x; 1.0897x over previous
//
#include <hip/hip_runtime.h>
#include <hip/hip_bf16.h>

// Problem constants (B=8, C=512, H=W=64, HEADS=8, HEAD_DIM=64)
#define BATCH 8
#define CDIM 512
#define NPIX 4096            // 64*64
#define NHEAD 8
#define HDIM 64
#define ATT_SCALE 0.125f     // HEAD_DIM^-0.5
#define L2EPS 1e-12f
#define STRIP 8              // y-rows per dwconv block

typedef __attribute__((ext_vector_type(8))) short short8;   // 8 bf16 (4 VGPRs)
typedef __attribute__((ext_vector_type(4))) short bf16x4;   // 4 bf16 (8B)
typedef __attribute__((ext_vector_type(4))) float f32x4;    // MFMA C/D

typedef const __attribute__((address_space(1))) void* gas_ptr;
typedef __attribute__((address_space(3))) void* las_ptr;

__device__ __forceinline__ void ld_lds16(const void* g, void* l) {
    // async global->LDS, 16B/lane. LDS dest = wave-uniform base + lane*16.
    __builtin_amdgcn_global_load_lds((gas_ptr)g, (las_ptr)l, 16, 0, 0);
}

__device__ __forceinline__ short f2bs(float f) {
    __hip_bfloat16 h = __float2bfloat16(f);
    return *reinterpret_cast<short*>(&h);
}

__device__ __forceinline__ float bs2f(short s) {
    unsigned u = ((unsigned)(unsigned short)s) << 16;
    return __builtin_bit_cast(float, u);
}

// ---------------------------------------------------------------------------
// shared 128x128-tile 2-phase GEMM core (round-1/2 verified): dbuf LDS,
// prefetch-issued-first, involution bank swizzle (slot ^= (row>>1)&3).
// ---------------------------------------------------------------------------
template <int KLEN, int ASTR, int BSTR>
__device__ __forceinline__ void gemm128_core(const short* __restrict__ Ag,
                                             const short* __restrict__ Bg,
                                             short* lds,   // [2][8192] shorts
                                             f32x4 acc[4][4], int tid) {
    const int wave = tid >> 6, lane = tid & 63;
    const int am = (wave >> 1) * 64, bn = (wave & 1) * 64;
    const int lrow = lane & 15;
    const int kslot = ((lane >> 4) ^ ((lrow >> 1) & 3)) * 8;
    const int sslot = ((lane & 3) ^ ((lane >> 3) & 3)) * 8;
    const int srow = wave * 16 + (lane >> 2);

    {
        short* As = lds;
        short* Bs = lds + 4096;
#pragma unroll
        for (int i = 0; i < 2; ++i) {
            const int r = srow + i * 64;
            const int off = (i * 256 + wave * 64) * 8;
            ld_lds16(Ag + (size_t)r * ASTR + sslot, As + off);
            ld_lds16(Bg + (size_t)r * BSTR + sslot, Bs + off);
        }
    }
    __syncthreads();

    int cur = 0;
    for (int k0 = 0; k0 < KLEN; k0 += 32) {
        if (k0 + 32 < KLEN) {
            short* As = lds + (cur ^ 1) * 8192;
            short* Bs = lds + (cur ^ 1) * 8192 + 4096;
#pragma unroll
            for (int i = 0; i < 2; ++i) {
                const int r = srow + i * 64;
                const int off = (i * 256 + wave * 64) * 8;
                ld_lds16(Ag + (size_t)r * ASTR + (k0 + 32) + sslot, As + off);
                ld_lds16(Bg + (size_t)r * BSTR + (k0 + 32) + sslot, Bs + off);
            }
        }
        const short* As = lds + cur * 8192;
        const short* Bs = lds + cur * 8192 + 4096;
        short8 afrag[4], bfrag[4];
#pragma unroll
        for (int i = 0; i < 4; ++i)
            afrag[i] = *(const short8*)&As[(am + i * 16 + lrow) * 32 + kslot];
#pragma unroll
        for (int j = 0; j < 4; ++j)
            bfrag[j] = *(const short8*)&Bs[(bn + j * 16 + lrow) * 32 + kslot];
#pragma unroll
        for (int i = 0; i < 4; ++i)
#pragma unroll
            for (int j = 0; j < 4; ++j)
                acc[i][j] = __builtin_amdgcn_mfma_f32_16x16x32_bf16(afrag[i], bfrag[j],
                                                                   acc[i][j], 0, 0, 0);
        __syncthreads();
        cur ^= 1;
    }
}

// ---------------------------------------------------------------------------
// 1) fused depthwise 3x3 (pad 1) + bf16 cast, TWO rows per barrier pair
//    (halves barrier count vs the R3 version; identical memory patterns).
//    Writes BOTH layouts: xd [b][c][n] and xdT [b][n][c].
// ---------------------------------------------------------------------------
__global__ __launch_bounds__(256) void dwconv_t(const float* __restrict__ x,
                                                const float* __restrict__ w,
                                                short* __restrict__ xd,
                                                short* __restrict__ xdT) {
    __shared__ float tile[2][16][65];
    const int t = threadIdx.x;
    const int lane = t & 63;          // x coordinate
    const int wv = t >> 6;            // 0..3
    const int y0 = blockIdx.x * STRIP;
    const int c0 = blockIdx.y * 16;
    const int b  = blockIdx.z;

    float wgt[4][9];
    float r0[4], r1[4], r2[4];
    const float* xb[4];
#pragma unroll
    for (int i = 0; i < 4; ++i) {
        const int c = c0 + wv * 4 + i;
        const float* wp = w + c * 9;
#pragma unroll
        for (int j = 0; j < 9; ++j) wgt[i][j] = wp[j];
        xb[i] = x + ((size_t)(b * CDIM + c)) * NPIX + lane;
        r0[i] = (y0 > 0) ? xb[i][(y0 - 1) * 64] : 0.f;
        r1[i] = xb[i][y0 * 64];
        r2[i] = xb[i][(y0 + 1) * 64];
    }

    for (int yy = 0; yy < STRIP; yy += 2) {
        const int y = y0 + yy;
        const bool l2 = (y + 2 < 64);
        const bool l3 = (yy < STRIP - 2) && (y + 3 < 64);
        float nA[4], nB[4];
#pragma unroll
        for (int i = 0; i < 4; ++i) {
            nA[i] = l2 ? xb[i][(y + 2) * 64] : 0.f;
            nB[i] = l3 ? xb[i][(y + 3) * 64] : 0.f;
        }

#pragma unroll
        for (int i = 0; i < 4; ++i) {
            // row y: window (r0, r1, r2)
            {
                float cl = wgt[i][0] * r0[i] + wgt[i][3] * r1[i] + wgt[i][6] * r2[i];
                float cm = wgt[i][1] * r0[i] + wgt[i][4] * r1[i] + wgt[i][7] * r2[i];
                float cr = wgt[i][2] * r0[i] + wgt[i][5] * r1[i] + wgt[i][8] * r2[i];
                float lft = __shfl_up(cl, 1);
                if (lane == 0) lft = 0.f;
                float rgt = __shfl_down(cr, 1);
                if (lane == 63) rgt = 0.f;
                const float val = lft + cm + rgt;
                tile[0][wv * 4 + i][lane] = val;
                xd[((size_t)(b * CDIM + c0 + wv * 4 + i)) * NPIX + y * 64 + lane]
                    = f2bs(val);
            }
            // row y+1: window (r1, r2, nA)
            {
                float cl = wgt[i][0] * r1[i] + wgt[i][3] * r2[i] + wgt[i][6] * nA[i];
                float cm = wgt[i][1] * r1[i] + wgt[i][4] * r2[i] + wgt[i][7] * nA[i];
                float cr = wgt[i][2] * r1[i] + wgt[i][5] * r2[i] + wgt[i][8] * nA[i];
                float lft = __shfl_up(cl, 1);
                if (lane == 0) lft = 0.f;
                float rgt = __shfl_down(cr, 1);
                if (lane == 63) rgt = 0.f;
                const float val = lft + cm + rgt;
                tile[1][wv * 4 + i][lane] = val;
                xd[((size_t)(b * CDIM + c0 + wv * 4 + i)) * NPIX + (y + 1) * 64 + lane]
                    = f2bs(val);
            }
        }
        __syncthreads();
        {
            const int n_l = t >> 2;
            const int cq = (t & 3) * 4;
#pragma unroll
            for (int s = 0; s < 2; ++s) {
                bf16x4 pk;
#pragma unroll
                for (int j = 0; j < 4; ++j) pk[j] = f2bs(tile[s][cq + j][n_l]);
                short* dst = xdT + ((size_t)b * NPIX + (y + s) * 64 + n_l) * CDIM + c0 + cq;
                *(bf16x4*)dst = pk;
            }
        }
        __syncthreads();
#pragma unroll
        for (int i = 0; i < 4; ++i) { r0[i] = r2[i]; r1[i] = nA[i]; r2[i] = nB[i]; }
    }
}

// ---------------------------------------------------------------------------
// 2) weight casts: q,k,v,proj natural bf16 + Wv TRANSPOSED bf16 (for M-assembly)
// ---------------------------------------------------------------------------
__global__ __launch_bounds__(256) void cast_weights(const float* __restrict__ s0,
                                                    const float* __restrict__ s1,
                                                    const float* __restrict__ s2,
                                                    const float* __restrict__ s3,
                                                    short* __restrict__ d0,
                                                    short* __restrict__ d1,
                                                    short* __restrict__ d2,
                                                    short* __restrict__ d3,
                                                    short* __restrict__ d4) {
    const int i = blockIdx.x * 256 + threadIdx.x;
    const int m = blockIdx.y;
    if (m < 4) {
        const float* s = (m == 0) ? s0 : (m == 1) ? s1 : (m == 2) ? s2 : s3;
        short* d = (m == 0) ? d0 : (m == 1) ? d1 : (m == 2) ? d2 : d3;
        d[i] = f2bs(s[i]);
    } else {
        // d4[c*512 + e] = bf16(v_w[e*512 + c])
        d4[i] = f2bs(s2[(size_t)(i & 511) * 512 + (i >> 9)]);
    }
}

// ---------------------------------------------------------------------------
// 3) Gram partials (R2 version): Gp[z][m][n'] = sum_{n in K-quarter}
//    xd[m,n]*xd[n',n], z = b*4 + kh (K split 4-ways: 512 blocks).
// ---------------------------------------------------------------------------
__global__ __launch_bounds__(256) void gram_part(const short* __restrict__ xd,
                                                 float* __restrict__ Gp) {
    __shared__ __align__(16) short lds[2 * 8192];
    const int tid = threadIdx.x;
    const int n0 = blockIdx.x * 128;
    const int m0 = blockIdx.y * 128;
    const int z  = blockIdx.z;
    const int b = z >> 2, kh = z & 3;
    const short* Ag = xd + ((size_t)(b * CDIM + m0)) * NPIX + kh * 1024;
    const short* Bg = xd + ((size_t)(b * CDIM + n0)) * NPIX + kh * 1024;
    f32x4 acc[4][4] = {};
    gemm128_core<1024, NPIX, NPIX>(Ag, Bg, lds, acc, tid);

    const int wave = tid >> 6, lane = tid & 63;
    const int am = (wave >> 1) * 64, bn = (wave & 1) * 64;
    const int crow = (lane >> 4) * 4, ccol = lane & 15;
    float* outp = Gp + (size_t)z * 262144;
#pragma unroll
    for (int i = 0; i < 4; ++i)
#pragma unroll
        for (int j = 0; j < 4; ++j)
#pragma unroll
            for (int r = 0; r < 4; ++r)
                outp[(size_t)(m0 + am + i * 16 + crow + r) * 512 + n0 + bn + j * 16 + ccol]
                    = acc[i][j][r];
}

// ---------------------------------------------------------------------------
// 4) reduce 4 Gram partials + cast to bf16 (R2 straight vectorized version)
// ---------------------------------------------------------------------------
__global__ __launch_bounds__(256) void gram_cast(const float* __restrict__ Gp,
                                                 short* __restrict__ G16) {
    const int i4 = blockIdx.x * 256 + threadIdx.x;   // 524288 threads
    const int b = i4 >> 16;
    const int r4 = (i4 & 65535) * 4;
    const float* base = Gp + (size_t)(4 * b) * 262144 + r4;
    f32x4 s0 = *(const f32x4*)&base[0];
    f32x4 s1 = *(const f32x4*)&base[262144];
    f32x4 s2 = *(const f32x4*)&base[2 * 262144];
    f32x4 s3 = *(const f32x4*)&base[3 * 262144];
    bf16x4 o;
#pragma unroll
    for (int t = 0; t < 4; ++t) o[t] = f2bs(s0[t] + s1[t] + s2[t] + s3[t]);
    *(bf16x4*)&G16[(size_t)b * 262144 + r4] = o;
}

// ---------------------------------------------------------------------------
// 5) [Wq;Wk;Wv] x G  -> QKVG[b][1536][512] bf16 (G symmetric: rows as B-op)
// ---------------------------------------------------------------------------
__global__ __launch_bounds__(256) void gemm_qkvG(const short* __restrict__ Wq,
                                                 const short* __restrict__ Wk,
                                                 const short* __restrict__ Wv,
                                                 const short* __restrict__ G16,
                                                 short* __restrict__ QKVG) {
    __shared__ __align__(16) short lds[2 * 8192];
    const int tid = threadIdx.x;
    const int n0 = blockIdx.x * 128;
    const int ot = blockIdx.y;                 // 0..11
    const int g = ot >> 2, o0 = (ot & 3) * 128;
    const int b = blockIdx.z;
    const short* W = (g == 0) ? Wq : (g == 1) ? Wk : Wv;
    const short* Ag = W + (size_t)o0 * CDIM;
    const short* Bg = G16 + (size_t)b * 262144 + (size_t)n0 * 512;
    f32x4 acc[4][4] = {};
    gemm128_core<512, 512, 512>(Ag, Bg, lds, acc, tid);

    const int wave = tid >> 6, lane = tid & 63;
    const int am = (wave >> 1) * 64, bn = (wave & 1) * 64;
    const int crow = (lane >> 4) * 4, ccol = lane & 15;
    short* Yg = QKVG + ((size_t)b * 1536 + g * 512 + o0) * 512;
#pragma unroll
    for (int i = 0; i < 4; ++i)
#pragma unroll
        for (int j = 0; j < 4; ++j)
#pragma unroll
            for (int r = 0; r < 4; ++r)
                Yg[(size_t)(am + i * 16 + crow + r) * 512 + n0 + bn + j * 16 + ccol]
                    = f2bs(acc[i][j][r]);
}

// ---------------------------------------------------------------------------
// 6) norms: rnorm[m][b][row] = 1/max(sqrt(QKVG[b][m,row,:] . W_m[row,:]), eps)
// ---------------------------------------------------------------------------
__global__ __launch_bounds__(256) void norms_dot(const short* __restrict__ QKVG,
                                                 const short* __restrict__ Wq,
                                                 const short* __restrict__ Wk,
                                                 const short* __restrict__ Wv,
                                                 float* __restrict__ rnorm) {
    const int tid = threadIdx.x, w = tid >> 6, lane = tid & 63;
#pragma unroll
    for (int it = 0; it < 4; ++it) {
        const int R = blockIdx.x * 16 + w * 4 + it;      // 0..12287
        const int b = R / 1536;
        const int mr = R - b * 1536;
        const int m = mr >> 9, row = mr & 511;
        const short* qr = QKVG + (size_t)R * 512 + lane * 8;
        const short* wr = ((m == 0) ? Wq : (m == 1) ? Wk : Wv) + (size_t)row * 512 + lane * 8;
        short8 a = *(const short8*)qr;
        short8 ww = *(const short8*)wr;
        float s = 0.f;
#pragma unroll
        for (int t = 0; t < 8; ++t) s += bs2f(a[t]) * bs2f(ww[t]);
        s += __shfl_xor(s, 1);  s += __shfl_xor(s, 2);
        s += __shfl_xor(s, 4);  s += __shfl_xor(s, 8);
        s += __shfl_xor(s, 16); s += __shfl_xor(s, 32);
        if (lane == 0)
            rnorm[m * 4096 + b * 512 + row] = 1.f / fmaxf(sqrtf(fmaxf(s, 0.f)), L2EPS);
    }
}

// ---------------------------------------------------------------------------
// 7) per-(b,h): A1 = QG_h * Wk_h^T (64x64, K=512) -> softmax (+norm scales,
//    rv folded) -> MT[b][c][h*64+d] = sum_e WvT[c][h*64+e] * P'[d][e].
//    blockIdx.y in [0,4): each block assembles 128 of the 512 c-rows
//    (QK+softmax recomputed per block -- bit-identical, cheap).
// ---------------------------------------------------------------------------
__global__ __launch_bounds__(256) void attn_small(const short* __restrict__ QKVG,
                                                  const short* __restrict__ Wk,
                                                  const short* __restrict__ WvT,
                                                  const float* __restrict__ rnorm,
                                                  short* __restrict__ MT) {
    __shared__ __align__(16) short Qs[64 * 32];
    __shared__ __align__(16) short Ks[64 * 32];
    __shared__ __align__(16) short Pl[64 * 72];
    const int tid = threadIdx.x, wave = tid >> 6, lane = tid & 63;
    const int bh = blockIdx.x, b = bh >> 3, h = bh & 7;
    const int cq = blockIdx.y;                 // c-quarter for MT assembly
    const int lrow = lane & 15;
    const int kslot = ((lane >> 4) ^ ((lrow >> 1) & 3)) * 8;
    const int sslot = ((lane & 3) ^ ((lane >> 3) & 3)) * 8;
    const int srow = tid >> 2;
    const short* qg = QKVG + ((size_t)b * 1536 + h * 64) * 512;   // QG rows d
    const short* kg = Wk + (size_t)(h * 64) * 512;                // Wk_h rows e
    f32x4 acc[4] = {};
    for (int k0 = 0; k0 < 512; k0 += 32) {
        ld_lds16(qg + (size_t)srow * 512 + k0 + sslot, Qs + wave * 512);
        ld_lds16(kg + (size_t)srow * 512 + k0 + sslot, Ks + wave * 512);
        __syncthreads();
        short8 af = *(const short8*)&Qs[(wave * 16 + lrow) * 32 + kslot];
#pragma unroll
        for (int j = 0; j < 4; ++j) {
            short8 bf = *(const short8*)&Ks[(j * 16 + lrow) * 32 + kslot];
            acc[j] = __builtin_amdgcn_mfma_f32_16x16x32_bf16(af, bf, acc[j], 0, 0, 0);
        }
        __syncthreads();
    }
    const int crow = (lane >> 4) * 4, ccol = lane & 15;
    const float* rq = rnorm + bh * 64;
    const float* rk = rnorm + 4096 + bh * 64;
    const float* rv = rnorm + 8192 + bh * 64;
    float rkv[4], rvv[4];
#pragma unroll
    for (int j = 0; j < 4; ++j) { rkv[j] = rk[j * 16 + ccol]; rvv[j] = rv[j * 16 + ccol]; }
#pragma unroll
    for (int r = 0; r < 4; ++r) {
        const int row = wave * 16 + crow + r;                    // d
        const float rqs = ATT_SCALE * rq[row];
        float L[4];
#pragma unroll
        for (int j = 0; j < 4; ++j) L[j] = acc[j][r] * rqs * rkv[j];
        float m = fmaxf(fmaxf(L[0], L[1]), fmaxf(L[2], L[3]));
        m = fmaxf(m, __shfl_xor(m, 1)); m = fmaxf(m, __shfl_xor(m, 2));
        m = fmaxf(m, __shfl_xor(m, 4)); m = fmaxf(m, __shfl_xor(m, 8));
        float p[4], s = 0.f;
#pragma unroll
        for (int j = 0; j < 4; ++j) { p[j] = expf(L[j] - m); s += p[j]; }
        s += __shfl_xor(s, 1); s += __shfl_xor(s, 2);
        s += __shfl_xor(s, 4); s += __shfl_xor(s, 8);
        const float inv = 1.f / s;
#pragma unroll
        for (int j = 0; j < 4; ++j)
            Pl[row * 72 + j * 16 + ccol] = f2bs(p[j] * inv * rvv[j]);
    }
    __syncthreads();
    // MT assembly (this block's 128 c-rows): C[c][d] = sum_e WvT[c][he] P'[d][e]
    const int lk2 = (lane >> 4) * 8;
    const short* wvt = WvT + h * 64;
    const int am2 = cq * 128 + wave * 32;
    f32x4 acc2[2][4] = {};
#pragma unroll
    for (int ks = 0; ks < 2; ++ks) {
        short8 bfr[4];
#pragma unroll
        for (int j2 = 0; j2 < 4; ++j2)
            bfr[j2] = *(const short8*)&Pl[(j2 * 16 + lrow) * 72 + ks * 32 + lk2];
#pragma unroll
        for (int i2 = 0; i2 < 2; ++i2) {
            short8 afr = *(const short8*)&wvt[(size_t)(am2 + i2 * 16 + lrow) * 512 + ks * 32 + lk2];
#pragma unroll
            for (int j2 = 0; j2 < 4; ++j2)
                acc2[i2][j2] = __builtin_amdgcn_mfma_f32_16x16x32_bf16(afr, bfr[j2],
                                                                      acc2[i2][j2], 0, 0, 0);
        }
    }
#pragma unroll
    for (int i2 = 0; i2 < 2; ++i2)
#pragma unroll
        for (int j2 = 0; j2 < 4; ++j2)
#pragma unroll
            for (int r = 0; r < 4; ++r)
                MT[((size_t)b * 512 + am2 + i2 * 16 + crow + r) * 512 + h * 64 + j2 * 16 + ccol]
                    = f2bs(acc2[i2][j2][r]);
}

// ---------------------------------------------------------------------------
// 8) F = Wp * M  (B-operand = MT rows, K=m) -> bf16 F[b][o][c]
// ---------------------------------------------------------------------------
__global__ __launch_bounds__(256) void gemm_projF(const short* __restrict__ Wp,
                                                  const short* __restrict__ MT,
                                                  short* __restrict__ F) {
    __shared__ __align__(16) short lds[2 * 8192];
    const int tid = threadIdx.x;
    const int n0 = blockIdx.x * 128;      // c
    const int o0 = blockIdx.y * 128;      // o
    const int b  = blockIdx.z;
    const short* Ag = Wp + (size_t)o0 * CDIM;
    const short* Bg = MT + (size_t)b * 262144 + (size_t)n0 * 512;
    f32x4 acc[4][4] = {};
    gemm128_core<512, 512, 512>(Ag, Bg, lds, acc, tid);

    const int wave = tid >> 6, lane = tid & 63;
    const int am = (wave >> 1) * 64, bn = (wave & 1) * 64;
    const int crow = (lane >> 4) * 4, ccol = lane & 15;
    short* Fg = F + (size_t)b * 262144;
#pragma unroll
    for (int i = 0; i < 4; ++i)
#pragma unroll
        for (int j = 0; j < 4; ++j)
#pragma unroll
            for (int r = 0; r < 4; ++r)
                Fg[(size_t)(o0 + am + i * 16 + crow + r) * 512 + n0 + bn + j * 16 + ccol]
                    = f2bs(acc[i][j][r]);
}

// ---------------------------------------------------------------------------
// 9) out = F * xd  (B-operand = xdT rows, K=c) -> fp32 out[b][o][n]
// ---------------------------------------------------------------------------
__global__ __launch_bounds__(256) void gemm_final(const short* __restrict__ F,
                                                  const short* __restrict__ XT,
                                                  float* __restrict__ Y) {
    __shared__ __align__(16) short lds[2 * 8192];
    const int tid = threadIdx.x;
    const int n0 = blockIdx.x * 128;
    const int o0 = blockIdx.y * 128;
    const int b  = blockIdx.z;
    const short* Ag = F + (size_t)b * 262144 + (size_t)o0 * 512;
    const short* Bg = XT + ((size_t)b * NPIX + n0) * CDIM;
    f32x4 acc[4][4] = {};
    gemm128_core<512, 512, 512>(Ag, Bg, lds, acc, tid);

    const int wave = tid >> 6, lane = tid & 63;
    const int am = (wave >> 1) * 64, bn = (wave & 1) * 64;
    const int crow = (lane >> 4) * 4, ccol = lane & 15;
#pragma unroll
    for (int i = 0; i < 4; ++i)
#pragma unroll
        for (int j = 0; j < 4; ++j)
#pragma unroll
            for (int r = 0; r < 4; ++r) {
                const int om = o0 + am + i * 16 + crow + r;
                const int on = n0 + bn + j * 16 + ccol;
                Y[((size_t)(b * CDIM + om)) * NPIX + on] = acc[i][j][r];
            }
}

// ---------------------------------------------------------------------------
extern "C" void kernel_launch(void* const* d_in, const int* in_sizes, int n_in,
                              void* d_out, int out_size, void* d_ws, size_t ws_size,
                              hipStream_t stream) {
    (void)in_sizes; (void)n_in; (void)out_size; (void)ws_size;
    const float* x      = (const float*)d_in[0];
    const float* dw_w   = (const float*)d_in[1];
    const float* q_w    = (const float*)d_in[2];
    const float* k_w    = (const float*)d_in[3];
    const float* v_w    = (const float*)d_in[4];
    const float* proj_w = (const float*)d_in[5];
    float* out = (float*)d_out;

    const size_t SZ = (size_t)BATCH * CDIM * NPIX;    // 16,777,216 elements
    short* xd   = (short*)d_ws;                        // SZ shorts (32 MB)
    short* xdT  = xd + SZ;                             // SZ shorts (32 MB)
    float* Gp   = (float*)(xdT + SZ);                  // 32 * 262144 fp32 (33.5 MB)
    short* G16  = (short*)(Gp + (size_t)32 * 262144);  // 8 * 262144 bf16 (4 MB)
    short* QKVG = G16 + (size_t)8 * 262144;            // 8*1536*512 bf16 (12 MB)
    float* rnorm= (float*)(QKVG + (size_t)8 * 1536 * 512);  // 3*8*512 fp32
    short* MTb  = (short*)(rnorm + 12288);             // 8*512*512 bf16 (4 MB)
    short* Fb   = MTb + (size_t)8 * 262144;            // 8*512*512 bf16 (4 MB)
    short* wqb  = Fb + (size_t)8 * 262144;             // 5 x 262144 bf16
    short* wkb  = wqb + 262144;
    short* wvb  = wkb + 262144;
    short* wpb  = wvb + 262144;
    short* wvtb = wpb + 262144;

    // 1) fused dwconv3x3 + bf16 cast -> xd [b][c][n] and xdT [b][n][c]
    dwconv_t<<<dim3(64 / STRIP, CDIM / 16, BATCH), 256, 0, stream>>>(x, dw_w, xd, xdT);

    // 2) weights -> bf16 (+ transposed Wv)
    cast_weights<<<dim3(1024, 5), 256, 0, stream>>>(q_w, k_w, v_w, proj_w,
                                                    wqb, wkb, wvb, wpb, wvtb);

    // 3) Gram partials (K split 4-ways: 512 blocks) + 4) reduce/cast
    gram_part<<<dim3(4, 4, 32), 256, 0, stream>>>(xd, Gp);
    gram_cast<<<dim3(2048), 256, 0, stream>>>(Gp, G16);

    // 5) [Wq;Wk;Wv] x G
    gemm_qkvG<<<dim3(4, 12, 8), 256, 0, stream>>>(wqb, wkb, wvb, G16, QKVG);

    // 6) L2-norm reciprocals (quadratic-form diagonals)
    norms_dot<<<dim3(768), 256, 0, stream>>>(QKVG, wqb, wkb, wvb, rnorm);

    // 7) per-head 64x64 attention + split M^T assembly (256 blocks)
    attn_small<<<dim3(64, 4), 256, 0, stream>>>(QKVG, wkb, wvtb, rnorm, MTb);

    // 8) F = Wp * M
    gemm_projF<<<dim3(4, 4, 8), 256, 0, stream>>>(wpb, MTb, Fb);

    // 9) out = F * xd
    gemm_final<<<dim3(32, 4, 8), 256, 0, stream>>>(Fb, xdT, out);
}